// Round 1
// baseline (215.145 us; speedup 1.0000x reference)
//
#include <hip/hip_runtime.h>
#include <math.h>

#define N_STATES 32
#define N_TYPES 128
#define N_GENES 8192
#define N_SAMPLES 8192
#define LOG2PI_F 1.8378770664093453f

// ---------------- Kernel 1: per-(state,gene) tables ----------------
// mu[st,g]  = sum_t cp[st,t] * Zmu[t,g]
// sigma     = sum_t cp^2 * Zs  +  (sum_t cp*Zs)^2  -  sum_t cp^2 * Zs^2
// store mu, inv = 1/sigma, lc = log(sigma) + 0.5*log(2pi)
__global__ __launch_bounds__(256) void precompute_kernel(
    const float* __restrict__ cp, const float* __restrict__ Zmu,
    const float* __restrict__ Zs, float* __restrict__ muT,
    float* __restrict__ invT, float* __restrict__ lcT) {
  __shared__ float s_cp[8][N_TYPES];
  __shared__ float s_cp2[8][N_TYPES];
  const int st0 = blockIdx.y * 8;
  const int g = blockIdx.x * 256 + threadIdx.x;

  for (int idx = threadIdx.x; idx < 8 * N_TYPES; idx += 256) {
    int s = idx >> 7, t = idx & (N_TYPES - 1);
    float c = cp[(st0 + s) * N_TYPES + t];
    s_cp[s][t] = c;
    s_cp2[s][t] = c * c;
  }
  __syncthreads();

  float mu_a[8], s1[8], s2[8], s3[8];
#pragma unroll
  for (int s = 0; s < 8; ++s) { mu_a[s] = 0.f; s1[s] = 0.f; s2[s] = 0.f; s3[s] = 0.f; }

  for (int t = 0; t < N_TYPES; ++t) {
    float zm = Zmu[t * N_GENES + g];
    float zs = Zs[t * N_GENES + g];
    float zs2 = zs * zs;
#pragma unroll
    for (int s = 0; s < 8; ++s) {
      mu_a[s] = fmaf(s_cp[s][t], zm, mu_a[s]);
      s1[s]   = fmaf(s_cp2[s][t], zs, s1[s]);
      s2[s]   = fmaf(s_cp[s][t], zs, s2[s]);
      s3[s]   = fmaf(s_cp2[s][t], zs2, s3[s]);
    }
  }

#pragma unroll
  for (int s = 0; s < 8; ++s) {
    float sigma = s1[s] + s2[s] * s2[s] - s3[s];
    int o = (st0 + s) * N_GENES + g;
    muT[o]  = mu_a[s];
    invT[o] = 1.0f / sigma;
    lcT[o]  = logf(sigma) + 0.5f * LOG2PI_F;
  }
}

// ---------------- Kernel 2: main elementwise + partial reduction ----------------
__global__ __launch_bounds__(256) void main_kernel(
    const float* __restrict__ X, const int* __restrict__ day,
    const float* __restrict__ muT, const float* __restrict__ invT,
    const float* __restrict__ lcT, float* __restrict__ out,
    float* __restrict__ partial) {
  const int NG4 = N_GENES / 4;                  // 2048 float4 per row
  const int total = N_SAMPLES * NG4;            // 16,777,216
  const float4* X4 = (const float4*)X;

  float acc = 0.f;
  for (int c = blockIdx.x * blockDim.x + threadIdx.x; c < total;
       c += gridDim.x * blockDim.x) {
    int i  = c >> 11;                           // sample row (2048 f4/row)
    int g4 = c & (NG4 - 1);
    int st = day[i] - 1;

    float4 x  = X4[c];
    float4 m  = ((const float4*)(muT  + st * N_GENES))[g4];
    float4 iv = ((const float4*)(invT + st * N_GENES))[g4];
    float4 l  = ((const float4*)(lcT  + st * N_GENES))[g4];

    float z0 = (x.x - m.x) * iv.x;
    float z1 = (x.y - m.y) * iv.y;
    float z2 = (x.z - m.z) * iv.z;
    float z3 = (x.w - m.w) * iv.w;
    float p0 = fmaf(-0.5f * z0, z0, -l.x);
    float p1 = fmaf(-0.5f * z1, z1, -l.y);
    float p2 = fmaf(-0.5f * z2, z2, -l.z);
    float p3 = fmaf(-0.5f * z3, z3, -l.w);

    size_t ob = (size_t)c * 4 + 1;              // +1: d_out[0] is the scalar sum
    out[ob]     = p0;
    out[ob + 1] = p1;
    out[ob + 2] = p2;
    out[ob + 3] = p3;

    acc += (p0 + p1) + (p2 + p3);
  }

  // wave(64) reduce then cross-wave via LDS
#pragma unroll
  for (int off = 32; off; off >>= 1) acc += __shfl_down(acc, off, 64);
  __shared__ float s_w[4];
  int lane = threadIdx.x & 63, w = threadIdx.x >> 6;
  if (lane == 0) s_w[w] = acc;
  __syncthreads();
  if (threadIdx.x == 0)
    partial[blockIdx.x] = (s_w[0] + s_w[1]) + (s_w[2] + s_w[3]);
}

// ---------------- Kernel 3: final reduction (deterministic, double) ----------------
__global__ __launch_bounds__(256) void reduce_kernel(
    const float* __restrict__ partial, int n, float* __restrict__ out0) {
  double acc = 0.0;
  for (int i = threadIdx.x; i < n; i += 256) acc += (double)partial[i];
#pragma unroll
  for (int off = 32; off; off >>= 1) acc += __shfl_down(acc, off, 64);
  __shared__ double s_w[4];
  int lane = threadIdx.x & 63, w = threadIdx.x >> 6;
  if (lane == 0) s_w[w] = acc;
  __syncthreads();
  if (threadIdx.x == 0) out0[0] = (float)((s_w[0] + s_w[1]) + (s_w[2] + s_w[3]));
}

extern "C" void kernel_launch(void* const* d_in, const int* in_sizes, int n_in,
                              void* d_out, int out_size, void* d_ws, size_t ws_size,
                              hipStream_t stream) {
  const float* cp  = (const float*)d_in[0];   // (32,128)
  const float* Zmu = (const float*)d_in[1];   // (128,8192)
  const float* Zs  = (const float*)d_in[2];   // (128,8192)
  const float* X   = (const float*)d_in[3];   // (8192,8192)
  const int*   day = (const int*)d_in[4];     // (8192,)
  float* out = (float*)d_out;                 // [0]=sum, [1..]=logp flat
  float* ws  = (float*)d_ws;

  const int TBL = N_STATES * N_GENES;         // 262144 floats per table
  float* muT     = ws;
  float* invT    = ws + TBL;
  float* lcT     = ws + 2 * TBL;
  float* partial = ws + 3 * TBL;

  dim3 g1(N_GENES / 256, N_STATES / 8);       // 32 x 4 blocks
  precompute_kernel<<<g1, 256, 0, stream>>>(cp, Zmu, Zs, muT, invT, lcT);

  const int NBLK = 2048;
  main_kernel<<<NBLK, 256, 0, stream>>>(X, day, muT, invT, lcT, out, partial);
  reduce_kernel<<<1, 256, 0, stream>>>(partial, NBLK, out);
}

// Round 2
// 187.956 us; speedup vs baseline: 1.1447x; 1.1447x over previous
//
#include <hip/hip_runtime.h>
#include <math.h>

#define N_STATES 32
#define N_TYPES 128
#define N_GENES 8192
#define N_SAMPLES 8192
#define LOG2PI_F 1.8378770664093453f

typedef float f32x4 __attribute__((ext_vector_type(4)));

// ---------------- Kernel 1: per-(state,gene) tables ----------------
// mu[st,g] = sum_t cp*Zmu ; sigma = sum_t cp^2*zs*(1-zs) + (sum_t cp*zs)^2
// store mu, inv = 1/sigma, lc = log(sigma) + 0.5*log(2pi)
__global__ __launch_bounds__(256) void precompute_kernel(
    const float* __restrict__ cp, const float* __restrict__ Zmu,
    const float* __restrict__ Zs, float* __restrict__ muT,
    float* __restrict__ invT, float* __restrict__ lcT) {
  __shared__ float s_cp[2][N_TYPES];
  __shared__ float s_cp2[2][N_TYPES];
  const int st0 = blockIdx.y * 2;
  const int g0 = (blockIdx.x * 256 + threadIdx.x) * 4;

  for (int idx = threadIdx.x; idx < 2 * N_TYPES; idx += 256) {
    int s = idx >> 7, t = idx & (N_TYPES - 1);
    float c = cp[(st0 + s) * N_TYPES + t];
    s_cp[s][t] = c;
    s_cp2[s][t] = c * c;
  }
  __syncthreads();

  float mu[2][4], s13[2][4], s2[2][4];
#pragma unroll
  for (int s = 0; s < 2; ++s)
#pragma unroll
    for (int j = 0; j < 4; ++j) { mu[s][j] = 0.f; s13[s][j] = 0.f; s2[s][j] = 0.f; }

  for (int t = 0; t < N_TYPES; ++t) {
    f32x4 zm = *(const f32x4*)(Zmu + t * N_GENES + g0);
    f32x4 zs = *(const f32x4*)(Zs + t * N_GENES + g0);
#pragma unroll
    for (int s = 0; s < 2; ++s) {
      float c = s_cp[s][t], c2 = s_cp2[s][t];
#pragma unroll
      for (int j = 0; j < 4; ++j) {
        mu[s][j]  = fmaf(c, zm[j], mu[s][j]);
        s2[s][j]  = fmaf(c, zs[j], s2[s][j]);
        s13[s][j] = fmaf(c2, zs[j] * (1.f - zs[j]), s13[s][j]);
      }
    }
  }

#pragma unroll
  for (int s = 0; s < 2; ++s) {
    f32x4 mv, iv, lv;
#pragma unroll
    for (int j = 0; j < 4; ++j) {
      float sigma = s13[s][j] + s2[s][j] * s2[s][j];
      mv[j] = mu[s][j];
      iv[j] = 1.0f / sigma;
      lv[j] = logf(sigma) + 0.5f * LOG2PI_F;
    }
    int o = (st0 + s) * N_GENES + g0;
    *(f32x4*)(muT + o)  = mv;
    *(f32x4*)(invT + o) = iv;
    *(f32x4*)(lcT + o)  = lv;
  }
}

// ---------------- Kernel 2: main elementwise + partial reduction ----------------
__global__ __launch_bounds__(256) void main_kernel(
    const float* __restrict__ X, const int* __restrict__ day,
    const float* __restrict__ muT, const float* __restrict__ invT,
    const float* __restrict__ lcT, float* __restrict__ out,
    float* __restrict__ partial) {
  const int NG4 = N_GENES / 4;                  // 2048 float4 per row
  const int total = N_SAMPLES * NG4;            // 16,777,216 chunks
  const f32x4* X4 = (const f32x4*)X;
  f32x4* out4 = (f32x4*)out;                    // out4[c] = out[4c..4c+3], aligned
  const int lane = threadIdx.x & 63;

  float acc = 0.f;
  for (int c = blockIdx.x * blockDim.x + threadIdx.x; c < total;
       c += gridDim.x * blockDim.x) {
    int i  = c >> 11;                           // sample row
    int g4 = c & (NG4 - 1);
    int st = day[i] - 1;

    f32x4 x  = X4[c];
    f32x4 m  = ((const f32x4*)(muT  + st * N_GENES))[g4];
    f32x4 iv = ((const f32x4*)(invT + st * N_GENES))[g4];
    f32x4 l  = ((const f32x4*)(lcT  + st * N_GENES))[g4];

    float z0 = (x[0] - m[0]) * iv[0];
    float z1 = (x[1] - m[1]) * iv[1];
    float z2 = (x[2] - m[2]) * iv[2];
    float z3 = (x[3] - m[3]) * iv[3];
    float p0 = fmaf(-0.5f * z0, z0, -l[0]);
    float p1 = fmaf(-0.5f * z1, z1, -l[1]);
    float p2 = fmaf(-0.5f * z2, z2, -l[2]);
    float p3 = fmaf(-0.5f * z3, z3, -l[3]);

    // shifted store: out[4c..4c+3] = logp[4c-1..4c+2]  (out[0] fixed by reduce)
    float pm1 = __shfl_up(p3, 1, 64);
    if (lane == 0) {
      pm1 = 0.f;
      if (c > 0) {
        int idx = 4 * c - 1;
        int ii = idx >> 13;
        int gg = idx & (N_GENES - 1);
        int ss = day[ii] - 1;
        float z = (X[idx] - muT[ss * N_GENES + gg]) * invT[ss * N_GENES + gg];
        pm1 = fmaf(-0.5f * z, z, -lcT[ss * N_GENES + gg]);
      }
    }
    f32x4 w; w[0] = pm1; w[1] = p0; w[2] = p1; w[3] = p2;
    __builtin_nontemporal_store(w, &out4[c]);
    if (c == total - 1) out[(size_t)total * 4] = p3;   // last logp element

    acc += (p0 + p1) + (p2 + p3);
  }

#pragma unroll
  for (int off = 32; off; off >>= 1) acc += __shfl_down(acc, off, 64);
  __shared__ float s_w[4];
  int w = threadIdx.x >> 6;
  if (lane == 0) s_w[w] = acc;
  __syncthreads();
  if (threadIdx.x == 0)
    partial[blockIdx.x] = (s_w[0] + s_w[1]) + (s_w[2] + s_w[3]);
}

// ---------------- Kernel 3: final reduction (deterministic, double) ----------------
__global__ __launch_bounds__(256) void reduce_kernel(
    const float* __restrict__ partial, int n, float* __restrict__ out0) {
  double acc = 0.0;
  for (int i = threadIdx.x; i < n; i += 256) acc += (double)partial[i];
#pragma unroll
  for (int off = 32; off; off >>= 1) acc += __shfl_down(acc, off, 64);
  __shared__ double s_w[4];
  int lane = threadIdx.x & 63, w = threadIdx.x >> 6;
  if (lane == 0) s_w[w] = acc;
  __syncthreads();
  if (threadIdx.x == 0) out0[0] = (float)((s_w[0] + s_w[1]) + (s_w[2] + s_w[3]));
}

extern "C" void kernel_launch(void* const* d_in, const int* in_sizes, int n_in,
                              void* d_out, int out_size, void* d_ws, size_t ws_size,
                              hipStream_t stream) {
  const float* cp  = (const float*)d_in[0];   // (32,128)
  const float* Zmu = (const float*)d_in[1];   // (128,8192)
  const float* Zs  = (const float*)d_in[2];   // (128,8192)
  const float* X   = (const float*)d_in[3];   // (8192,8192)
  const int*   day = (const int*)d_in[4];     // (8192,)
  float* out = (float*)d_out;                 // [0]=sum, [1..]=logp flat
  float* ws  = (float*)d_ws;

  const int TBL = N_STATES * N_GENES;         // 262144 floats per table
  float* muT     = ws;
  float* invT    = ws + TBL;
  float* lcT     = ws + 2 * TBL;
  float* partial = ws + 3 * TBL;

  dim3 g1(N_GENES / 1024, N_STATES / 2);      // 8 x 16 = 128 blocks
  precompute_kernel<<<g1, 256, 0, stream>>>(cp, Zmu, Zs, muT, invT, lcT);

  const int NBLK = 2048;
  main_kernel<<<NBLK, 256, 0, stream>>>(X, day, muT, invT, lcT, out, partial);
  reduce_kernel<<<1, 256, 0, stream>>>(partial, NBLK, out);
}